// Round 1
// baseline (89.573 us; speedup 1.0000x reference)
//
#include <hip/hip_runtime.h>

#define GHMR_MU   0.02f
#define GHMR_BINS 30

// ---------------------------------------------------------------------------
// Kernel 1: zero the global bin accumulators in d_ws (harness poisons d_ws
// with 0xAA once and never re-poisons; we must re-zero every call).
// ---------------------------------------------------------------------------
__global__ void ghmr_init(float* __restrict__ g_sum, unsigned int* __restrict__ g_cnt) {
    int t = threadIdx.x;
    if (t < GHMR_BINS) { g_sum[t] = 0.0f; g_cnt[t] = 0u; }
}

// ---------------------------------------------------------------------------
// Kernel 2: single pass over all elements.
//   per-bin: sum of loss over valid elements, count of valid elements.
//   bin 29 (~96% of elements) accumulates in registers; rare bins via LDS.
// ---------------------------------------------------------------------------
__global__ __launch_bounds__(256) void ghmr_hist(
    const float4* __restrict__ pred,
    const float4* __restrict__ target,
    const float4* __restrict__ lw,
    float* __restrict__ g_sum,
    unsigned int* __restrict__ g_cnt,
    int n4)
{
    __shared__ float        s_sum[GHMR_BINS];
    __shared__ unsigned int s_cnt[GHMR_BINS];

    const int tid = threadIdx.x;
    if (tid < GHMR_BINS) { s_sum[tid] = 0.0f; s_cnt[tid] = 0u; }
    __syncthreads();

    const float mu  = GHMR_MU;
    const float mu2 = GHMR_MU * GHMR_MU;

    float        sum29 = 0.0f;   // fast-path accumulator (bin 29)
    unsigned int cnt29 = 0u;

    const int stride = gridDim.x * blockDim.x;
    for (int i = blockIdx.x * blockDim.x + tid; i < n4; i += stride) {
        float4 p = pred[i];
        float4 t = target[i];
        float4 w = lw[i];
#pragma unroll
        for (int j = 0; j < 4; ++j) {
            float pj = (&p.x)[j];
            float tj = (&t.x)[j];
            float wj = (&w.x)[j];

            float d    = pj - tj;
            float d2   = fmaf(d, d, mu2);
            float r    = sqrtf(d2);
            float loss = r - mu;
            float g    = fabsf(d) * rsqrtf(d2);   // in [0,1)
            int   idx  = (int)(g * (float)GHMR_BINS);
            idx        = (idx > GHMR_BINS - 1) ? (GHMR_BINS - 1) : idx;
            bool valid = (wj > 0.0f);

            if (valid) {
                if (idx == GHMR_BINS - 1) {
                    sum29 += loss;
                    cnt29 += 1u;
                } else {
                    atomicAdd(&s_sum[idx], loss);
                    atomicAdd(&s_cnt[idx], 1u);
                }
            }
        }
    }

    // wave-level reduction of the fast-path accumulators (wave = 64 lanes)
    for (int off = 32; off > 0; off >>= 1) {
        sum29 += __shfl_down(sum29, off);
        cnt29 += (unsigned int)__shfl_down((int)cnt29, off);
    }
    if ((tid & 63) == 0) {
        atomicAdd(&s_sum[GHMR_BINS - 1], sum29);
        atomicAdd(&s_cnt[GHMR_BINS - 1], cnt29);
    }
    __syncthreads();

    // block -> global
    if (tid < GHMR_BINS) {
        atomicAdd(&g_sum[tid], s_sum[tid]);
        atomicAdd(&g_cnt[tid], s_cnt[tid]);
    }
}

// ---------------------------------------------------------------------------
// Kernel 3: finalize.  result = (1/n) * sum_b  S_b / max(c_b, 1)
// (tot cancels algebraically in the reference expression.)
// ---------------------------------------------------------------------------
__global__ void ghmr_final(const float* __restrict__ g_sum,
                           const unsigned int* __restrict__ g_cnt,
                           float* __restrict__ out)
{
    int b = threadIdx.x;   // 0..63
    float term = 0.0f;
    float nonz = 0.0f;
    if (b < GHMR_BINS) {
        unsigned int c = g_cnt[b];
        float        s = g_sum[b];
        term = s / fmaxf((float)c, 1.0f);
        nonz = (c > 0u) ? 1.0f : 0.0f;
    }
    for (int off = 32; off > 0; off >>= 1) {
        term += __shfl_down(term, off);
        nonz += __shfl_down(nonz, off);
    }
    if (b == 0) {
        out[0] = term / fmaxf(nonz, 1.0f);
    }
}

// ---------------------------------------------------------------------------
extern "C" void kernel_launch(void* const* d_in, const int* in_sizes, int n_in,
                              void* d_out, int out_size, void* d_ws, size_t ws_size,
                              hipStream_t stream) {
    const float4* pred   = (const float4*)d_in[0];
    const float4* target = (const float4*)d_in[1];
    const float4* lw     = (const float4*)d_in[2];

    int n  = in_sizes[0];      // B*C = 16,777,216 (divisible by 4)
    int n4 = n / 4;

    float*        g_sum = (float*)d_ws;
    unsigned int* g_cnt = (unsigned int*)((char*)d_ws + GHMR_BINS * sizeof(float));

    ghmr_init<<<1, 64, 0, stream>>>(g_sum, g_cnt);

    const int threads = 256;
    const int blocks  = 2048;   // 8 blocks/CU on 256 CUs, grid-stride
    ghmr_hist<<<blocks, threads, 0, stream>>>(pred, target, lw, g_sum, g_cnt, n4);

    ghmr_final<<<1, 64, 0, stream>>>(g_sum, g_cnt, (float*)d_out);
}